// Round 8
// baseline (323.485 us; speedup 1.0000x reference)
//
#include <hip/hip_runtime.h>
#include <hip/hip_bf16.h>

#define HIDDEN 256
#define NB 4            // batches
#define NQ 200          // queries
#define MT 13           // m-tiles of 16 (208 padded rows)
#define HW 65536        // 256*256 pixels
#define KSTEPS 8        // 256 / 32
#define NPB 128         // pixels per gemm tile
#define NTILE 8         // tiles per persistent block
#define GT 512          // gemm threads (8 waves)
#define BUFB 65536      // bytes per LDS panel

typedef __attribute__((ext_vector_type(8))) __bf16 bf16x8;
typedef __attribute__((ext_vector_type(4))) float f32x4;

#define WAIT_LGKM0() asm volatile("s_waitcnt lgkmcnt(0)" ::: "memory")
__device__ __forceinline__ void hard_barrier() {
    __builtin_amdgcn_sched_barrier(0);
    __builtin_amdgcn_s_barrier();
    __builtin_amdgcn_sched_barrier(0);
}

// ---------------------------------------------------------------------------
// Kernel 1: mask_embed MLP -> bf16 A-fragments in d_ws (unchanged, verified).
// A_ws layout: [b][mt][ks][lane(64)][j(8)] bf16,
//   element (row = mt*16 + (lane&15), k = ks*32 + (lane>>4)*8 + j)
// ---------------------------------------------------------------------------
__global__ __launch_bounds__(1024)
void mlp_pack(const float* __restrict__ queries,
              const float* __restrict__ w1, const float* __restrict__ b1,
              const float* __restrict__ w2, const float* __restrict__ b2,
              __bf16* __restrict__ A_ws)
{
    __shared__ float qh[16][HIDDEN];
    __shared__ float wb[HIDDEN][33];
    const int blk = blockIdx.x;
    const int b = blk / MT, mt = blk % MT;
    const int tid = threadIdx.x;

    for (int idx = tid; idx < 16 * HIDDEN; idx += 1024) {
        int r = idx >> 8, c = idx & 255;
        int q = mt * 16 + r;
        qh[r][c] = (q < NQ) ? queries[((size_t)b * NQ + q) * HIDDEN + c] : 0.f;
    }
    __syncthreads();

    const int t  = tid & 255;
    const int rq = tid >> 8;
    const int sr = tid >> 2;
    const int si = tid & 3;

    float h[4];
    #pragma unroll
    for (int r = 0; r < 4; ++r) h[r] = b1[t];
    for (int cc = 0; cc < 8; ++cc) {
        const float* src = w1 + (size_t)sr * HIDDEN + cc * 32;
        float4 va = *reinterpret_cast<const float4*>(src + si * 4);
        float4 vb = *reinterpret_cast<const float4*>(src + 16 + si * 4);
        wb[sr][si*4+0] = va.x; wb[sr][si*4+1] = va.y;
        wb[sr][si*4+2] = va.z; wb[sr][si*4+3] = va.w;
        wb[sr][16+si*4+0] = vb.x; wb[sr][16+si*4+1] = vb.y;
        wb[sr][16+si*4+2] = vb.z; wb[sr][16+si*4+3] = vb.w;
        __syncthreads();
        #pragma unroll
        for (int cl = 0; cl < 32; ++cl) {
            float w = wb[t][cl];
            #pragma unroll
            for (int r = 0; r < 4; ++r)
                h[r] = fmaf(qh[rq * 4 + r][cc * 32 + cl], w, h[r]);
        }
        __syncthreads();
    }

    #pragma unroll
    for (int r = 0; r < 4; ++r) qh[rq * 4 + r][t] = fmaxf(h[r], 0.f);
    __syncthreads();

    float me[4];
    #pragma unroll
    for (int r = 0; r < 4; ++r) me[r] = b2[t];
    for (int cc = 0; cc < 8; ++cc) {
        const float* src = w2 + (size_t)sr * HIDDEN + cc * 32;
        float4 va = *reinterpret_cast<const float4*>(src + si * 4);
        float4 vb = *reinterpret_cast<const float4*>(src + 16 + si * 4);
        wb[sr][si*4+0] = va.x; wb[sr][si*4+1] = va.y;
        wb[sr][si*4+2] = va.z; wb[sr][si*4+3] = va.w;
        wb[sr][16+si*4+0] = vb.x; wb[sr][16+si*4+1] = vb.y;
        wb[sr][16+si*4+2] = vb.z; wb[sr][16+si*4+3] = vb.w;
        __syncthreads();
        #pragma unroll
        for (int cl = 0; cl < 32; ++cl) {
            float w = wb[t][cl];
            #pragma unroll
            for (int r = 0; r < 4; ++r)
                me[r] = fmaf(qh[rq * 4 + r][cc * 32 + cl], w, me[r]);
        }
        __syncthreads();
    }

    const int ks = t >> 5, g = (t >> 3) & 3, j = t & 7;
    #pragma unroll
    for (int r = 0; r < 4; ++r) {
        int row = rq * 4 + r;
        int q = mt * 16 + row;
        float v = (q < NQ) ? me[r] : 0.f;
        int lane = row + 16 * g;
        size_t addr = ((size_t)((b * MT + mt) * KSTEPS + ks)) * 512 + (size_t)lane * 8 + j;
        A_ws[addr] = (__bf16)v;
    }
}

// ---------------------------------------------------------------------------
// Kernel 2 v7: persistent pipeline, 1 block/CU, 256-VGPR budget.
// __launch_bounds__(GT, 1): second arg behaves like CUDA min-blocks on this
// toolchain ((GT,2) capped VGPRs at 128 and spilled -> r5/r7 regression).
// 256 blocks x 8 waves; block owns batch (bid>>6) and 8 consecutive 128-px
// tiles. A-fragments resident (64 VGPR, loaded once; no vmem in K-loop).
// Per tile i:
//   [bar: panel[cur] ready] -> issue 64 reg-loads for tile i+1 ->
//   K-loop on panel[cur] (pure LDS+MFMA) -> [bar] ->
//   cvt+ds_write tile i+1 into panel[cur^1] (disjoint) ->
//   epilogue on panel[cur] scratch (nontemporal 512B row stores) -> loop.
// LDS element (n,k) at byte: n*512 + (((k>>3) ^ (n&7))<<4) + (k&7)*2.
// ---------------------------------------------------------------------------
__global__ __launch_bounds__(GT, 1)
void mask_gemm(const float* __restrict__ mf,
               const __bf16* __restrict__ A_ws,
               float* __restrict__ out)
{
    extern __shared__ char smem[];     // 2 x 64 KB panels

    const int bid = blockIdx.x;
    const int b   = bid >> 6;          // 64 blocks per batch
    const int tb  = (bid & 63) * NTILE;
    const int tid = threadIdx.x;
    const int ln  = tid & 63, wv = tid >> 6;
    const int l15 = ln & 15,  lg = ln >> 4;
    const bool has2 = (wv + 8) < MT;
    const int swz = l15 & 7;

    const float*  mfB  = mf  + (size_t)b * HIDDEN * HW;
    const __bf16* Ab   = A_ws + (size_t)b * (MT * KSTEPS * 512);
    float*        outB = out + (size_t)b * NQ * HW;

    // ---- A fragments: resident for the whole kernel (64 VGPR) ----
    bf16x8 Af[2][KSTEPS];
    #pragma unroll
    for (int ks = 0; ks < KSTEPS; ++ks)
        Af[0][ks] = *reinterpret_cast<const bf16x8*>(
            Ab + ((size_t)(wv * KSTEPS + ks)) * 512 + (size_t)ln * 8);
    if (has2) {
        #pragma unroll
        for (int ks = 0; ks < KSTEPS; ++ks)
            Af[1][ks] = *reinterpret_cast<const bf16x8*>(
                Ab + ((size_t)((wv + 8) * KSTEPS + ks)) * 512 + (size_t)ln * 8);
    }

    // ---- prologue: stage tile tb into panel 0 (register path) ----
    {
        const float* mfb = mfB + (size_t)tb * NPB;
        #pragma unroll
        for (int ch = 0; ch < 2; ++ch) {
            const int n = ch * 64 + ln;
            #pragma unroll
            for (int kb = 0; kb < 4; ++kb) {
                const int k0 = wv * 32 + kb * 8;
                float v8[8];
                #pragma unroll
                for (int j = 0; j < 8; ++j)
                    v8[j] = mfb[(size_t)(k0 + j) * HW + n];
                bf16x8 pk;
                #pragma unroll
                for (int j = 0; j < 8; ++j) pk[j] = (__bf16)v8[j];
                const int u = k0 >> 3;
                *reinterpret_cast<bf16x8*>(smem + n * 512 + ((u ^ (n & 7)) << 4)) = pk;
            }
        }
    }

    f32x4 acc[2][8];
    #pragma unroll
    for (int i2 = 0; i2 < 2; ++i2)
        #pragma unroll
        for (int f = 0; f < 8; ++f)
            acc[i2][f] = (f32x4){0.f, 0.f, 0.f, 0.f};

    // ---- persistent tile loop ----
    for (int i = 0; i < NTILE; ++i) {
        char* bcur = smem + (i & 1) * BUFB;
        char* bnxt = smem + ((i & 1) ^ 1) * BUFB;

        WAIT_LGKM0();
        hard_barrier();                    // panel[cur] staged & visible

        // issue ALL next-tile loads now; they fly during K-loop + epilogue
        float v[64];
        const bool havenext = (i + 1 < NTILE);
        if (havenext) {
            const float* mfb = mfB + (size_t)(tb + i + 1) * NPB;
            #pragma unroll
            for (int ch = 0; ch < 2; ++ch) {
                const int n = ch * 64 + ln;
                #pragma unroll
                for (int kb = 0; kb < 4; ++kb) {
                    const int k0 = wv * 32 + kb * 8;
                    #pragma unroll
                    for (int j = 0; j < 8; ++j)
                        v[ch * 32 + kb * 8 + j] = mfb[(size_t)(k0 + j) * HW + n];
                }
            }
            __builtin_amdgcn_sched_barrier(0);   // pin issuance before K-loop
        }

        // K-loop: pure LDS + MFMA (zero vmem -> no vmcnt coupling with loads)
        #pragma unroll
        for (int t = 0; t < KSTEPS; ++t) {
            #pragma unroll
            for (int fg = 0; fg < 2; ++fg) {
                bf16x8 bf[4];
                #pragma unroll
                for (int f2 = 0; f2 < 4; ++f2) {
                    const int f = fg * 4 + f2;
                    const int off = (f * 16 + l15) * 512 + (((t * 4 + lg) ^ swz) << 4);
                    bf[f2] = *reinterpret_cast<const bf16x8*>(bcur + off);
                }
                #pragma unroll
                for (int f2 = 0; f2 < 4; ++f2) {
                    acc[0][fg * 4 + f2] = __builtin_amdgcn_mfma_f32_16x16x32_bf16(
                        Af[0][t], bf[f2], acc[0][fg * 4 + f2], 0, 0, 0);
                    if (has2)
                        acc[1][fg * 4 + f2] = __builtin_amdgcn_mfma_f32_16x16x32_bf16(
                            Af[1][t], bf[f2], acc[1][fg * 4 + f2], 0, 0, 0);
                }
            }
        }
        __builtin_amdgcn_sched_barrier(0);
        WAIT_LGKM0();
        hard_barrier();                    // all waves done reading panel[cur]

        // stage-write tile i+1 into panel[cur^1] (disjoint regions; compiler
        // inserts the vmcnt waits for v[] as needed)
        if (havenext) {
            #pragma unroll
            for (int ch = 0; ch < 2; ++ch) {
                const int n = ch * 64 + ln;
                #pragma unroll
                for (int kb = 0; kb < 4; ++kb) {
                    const int k0 = wv * 32 + kb * 8;
                    bf16x8 pk;
                    #pragma unroll
                    for (int j = 0; j < 8; ++j) pk[j] = (__bf16)v[ch * 32 + kb * 8 + j];
                    const int u = k0 >> 3;
                    *reinterpret_cast<bf16x8*>(bnxt + n * 512 + ((u ^ (n & 7)) << 4)) = pk;
                }
            }
        }

        // epilogue: 7 passes, transpose via panel[cur] scratch, nt 512B stores
        {
            const int n0 = (tb + i) * NPB;
            float* scr  = reinterpret_cast<float*>(bcur);   // [32][132]
            float* outb = outB + n0;
            #pragma unroll
            for (int p = 0; p < 7; ++p) {
                WAIT_LGKM0();
                hard_barrier();            // prior pass reads (or bar above) done
                #pragma unroll
                for (int u = 0; u < 2; ++u) {
                    const int mt = 2 * p + u;
                    if (mt < MT && (mt & 7) == wv) {
                        const int ii = mt >> 3;
                        #pragma unroll
                        for (int f = 0; f < 8; ++f)
                            #pragma unroll
                            for (int r = 0; r < 4; ++r)
                                scr[(u * 16 + lg * 4 + r) * 132 + f * 16 + l15] =
                                    acc[ii][f][r];
                    }
                }
                WAIT_LGKM0();
                hard_barrier();            // transpose writes visible
                #pragma unroll
                for (int s = 0; s < 2; ++s) {
                    const int idx = tid + s * GT;
                    const int row = idx >> 5, c4 = (idx & 31) << 2;
                    const int q = p * 32 + row;
                    if (q < NQ) {
                        f32x4 vv = *reinterpret_cast<const f32x4*>(&scr[row * 132 + c4]);
                        __builtin_nontemporal_store(vv,
                            reinterpret_cast<f32x4*>(outb + (size_t)q * HW + c4));
                    }
                }
            }
        }

        // reset accumulators for next tile
        #pragma unroll
        for (int ii = 0; ii < 2; ++ii)
            #pragma unroll
            for (int f = 0; f < 8; ++f)
                acc[ii][f] = (f32x4){0.f, 0.f, 0.f, 0.f};
    }
}

// ---------------------------------------------------------------------------
extern "C" void kernel_launch(void* const* d_in, const int* in_sizes, int n_in,
                              void* d_out, int out_size, void* d_ws, size_t ws_size,
                              hipStream_t stream)
{
    const float* queries = (const float*)d_in[0];
    const float* mf      = (const float*)d_in[1];
    const float* w1      = (const float*)d_in[2];
    const float* b1      = (const float*)d_in[3];
    const float* w2      = (const float*)d_in[4];
    const float* b2      = (const float*)d_in[5];
    float*  out  = (float*)d_out;
    __bf16* A_ws = (__bf16*)d_ws;   // 4*13*8*512*2 = 425,984 B

    (void)hipFuncSetAttribute((const void*)mask_gemm,
                              hipFuncAttributeMaxDynamicSharedMemorySize, 2 * BUFB);

    hipLaunchKernelGGL(mlp_pack, dim3(NB * MT), dim3(1024), 0, stream,
                       queries, w1, b1, w2, b2, A_ws);
    hipLaunchKernelGGL(mask_gemm, dim3(256), dim3(GT), 2 * BUFB, stream,
                       mf, A_ws, out);
}

// Round 9
// 265.202 us; speedup vs baseline: 1.2198x; 1.2198x over previous
//
#include <hip/hip_runtime.h>
#include <hip/hip_bf16.h>

#define HIDDEN 256
#define NB 4            // batches
#define NQ 200          // queries
#define MT 13           // m-tiles of 16 (208 padded rows)
#define HW 65536        // 256*256 pixels
#define KSTEPS 8        // 256 / 32
#define NPB 128         // pixels per gemm tile
#define NTILE 8         // tiles per persistent block
#define GT 1024         // gemm threads (16 waves)
#define BUFB 65536      // bytes per LDS panel

typedef __attribute__((ext_vector_type(8))) __bf16 bf16x8;
typedef __attribute__((ext_vector_type(4))) float f32x4;

#define WAIT_LGKM0() asm volatile("s_waitcnt lgkmcnt(0)" ::: "memory")
__device__ __forceinline__ void hard_barrier() {
    __builtin_amdgcn_sched_barrier(0);
    __builtin_amdgcn_s_barrier();
    __builtin_amdgcn_sched_barrier(0);
}

// ---------------------------------------------------------------------------
// Kernel 1: mask_embed MLP -> bf16 A-fragments in d_ws (unchanged, verified).
// A_ws layout: [b][mt][ks][lane(64)][j(8)] bf16,
//   element (row = mt*16 + (lane&15), k = ks*32 + (lane>>4)*8 + j)
// ---------------------------------------------------------------------------
__global__ __launch_bounds__(1024)
void mlp_pack(const float* __restrict__ queries,
              const float* __restrict__ w1, const float* __restrict__ b1,
              const float* __restrict__ w2, const float* __restrict__ b2,
              __bf16* __restrict__ A_ws)
{
    __shared__ float qh[16][HIDDEN];
    __shared__ float wb[HIDDEN][33];
    const int blk = blockIdx.x;
    const int b = blk / MT, mt = blk % MT;
    const int tid = threadIdx.x;

    for (int idx = tid; idx < 16 * HIDDEN; idx += 1024) {
        int r = idx >> 8, c = idx & 255;
        int q = mt * 16 + r;
        qh[r][c] = (q < NQ) ? queries[((size_t)b * NQ + q) * HIDDEN + c] : 0.f;
    }
    __syncthreads();

    const int t  = tid & 255;
    const int rq = tid >> 8;
    const int sr = tid >> 2;
    const int si = tid & 3;

    float h[4];
    #pragma unroll
    for (int r = 0; r < 4; ++r) h[r] = b1[t];
    for (int cc = 0; cc < 8; ++cc) {
        const float* src = w1 + (size_t)sr * HIDDEN + cc * 32;
        float4 va = *reinterpret_cast<const float4*>(src + si * 4);
        float4 vb = *reinterpret_cast<const float4*>(src + 16 + si * 4);
        wb[sr][si*4+0] = va.x; wb[sr][si*4+1] = va.y;
        wb[sr][si*4+2] = va.z; wb[sr][si*4+3] = va.w;
        wb[sr][16+si*4+0] = vb.x; wb[sr][16+si*4+1] = vb.y;
        wb[sr][16+si*4+2] = vb.z; wb[sr][16+si*4+3] = vb.w;
        __syncthreads();
        #pragma unroll
        for (int cl = 0; cl < 32; ++cl) {
            float w = wb[t][cl];
            #pragma unroll
            for (int r = 0; r < 4; ++r)
                h[r] = fmaf(qh[rq * 4 + r][cc * 32 + cl], w, h[r]);
        }
        __syncthreads();
    }

    #pragma unroll
    for (int r = 0; r < 4; ++r) qh[rq * 4 + r][t] = fmaxf(h[r], 0.f);
    __syncthreads();

    float me[4];
    #pragma unroll
    for (int r = 0; r < 4; ++r) me[r] = b2[t];
    for (int cc = 0; cc < 8; ++cc) {
        const float* src = w2 + (size_t)sr * HIDDEN + cc * 32;
        float4 va = *reinterpret_cast<const float4*>(src + si * 4);
        float4 vb = *reinterpret_cast<const float4*>(src + 16 + si * 4);
        wb[sr][si*4+0] = va.x; wb[sr][si*4+1] = va.y;
        wb[sr][si*4+2] = va.z; wb[sr][si*4+3] = va.w;
        wb[sr][16+si*4+0] = vb.x; wb[sr][16+si*4+1] = vb.y;
        wb[sr][16+si*4+2] = vb.z; wb[sr][16+si*4+3] = vb.w;
        __syncthreads();
        #pragma unroll
        for (int cl = 0; cl < 32; ++cl) {
            float w = wb[t][cl];
            #pragma unroll
            for (int r = 0; r < 4; ++r)
                me[r] = fmaf(qh[rq * 4 + r][cc * 32 + cl], w, me[r]);
        }
        __syncthreads();
    }

    const int ks = t >> 5, g = (t >> 3) & 3, j = t & 7;
    #pragma unroll
    for (int r = 0; r < 4; ++r) {
        int row = rq * 4 + r;
        int q = mt * 16 + row;
        float v = (q < NQ) ? me[r] : 0.f;
        int lane = row + 16 * g;
        size_t addr = ((size_t)((b * MT + mt) * KSTEPS + ks)) * 512 + (size_t)lane * 8 + j;
        A_ws[addr] = (__bf16)v;
    }
}

// ---------------------------------------------------------------------------
// Kernel 2 v8: persistent pipeline sized to FIT the 128-VGPR budget.
// 1024 threads = 16 waves, 1 block/CU (128 KB LDS), 256 blocks.
// Wave wv owns m-tile wv (waves 13..15 idle in MFMA; all waves stage/store).
// Per-wave residents: Af[8]=32 regs, acc[8]=32 regs, v[32]=32 regs -> ~120.
// Per tile i:
//   [bar: panel ready] -> issue 32 reg-loads for tile i+1 ->
//   K-loop on panel[cur] (pure LDS+MFMA) -> [bar] ->
//   epilogue on panel[cur] scratch (nontemporal 512B row stores) ->
//   cvt+ds_write tile i+1 -> panel[cur^1]  (reads got K-loop+epilogue to land)
// LDS element (n,k) at byte: n*512 + (((k>>3) ^ (n&7))<<4) + (k&7)*2.
// ---------------------------------------------------------------------------
__global__ __launch_bounds__(GT)
void mask_gemm(const float* __restrict__ mf,
               const __bf16* __restrict__ A_ws,
               float* __restrict__ out)
{
    extern __shared__ char smem[];     // 2 x 64 KB panels

    const int bid = blockIdx.x;
    const int b   = bid >> 6;          // 64 blocks per batch
    const int tb  = (bid & 63) * NTILE;
    const int tid = threadIdx.x;
    const int ln  = tid & 63, wv = tid >> 6;   // wv in [0,16)
    const int l15 = ln & 15,  lg = ln >> 4;
    const bool hasmt = wv < MT;
    const int swz = l15 & 7;

    const float*  mfB  = mf  + (size_t)b * HIDDEN * HW;
    const __bf16* Ab   = A_ws + (size_t)b * (MT * KSTEPS * 512);
    float*        outB = out + (size_t)b * NQ * HW;

    // ---- A fragments: resident for the whole kernel (32 VGPR) ----
    bf16x8 Af[KSTEPS];
    if (hasmt) {
        #pragma unroll
        for (int ks = 0; ks < KSTEPS; ++ks)
            Af[ks] = *reinterpret_cast<const bf16x8*>(
                Ab + ((size_t)(wv * KSTEPS + ks)) * 512 + (size_t)ln * 8);
    }

    // ---- prologue: stage tile tb into panel 0 ----
    // wave wv stages k-rows [wv*16, wv*16+16), both 64-column halves
    {
        const float* mfb = mfB + (size_t)tb * NPB;
        #pragma unroll
        for (int ch = 0; ch < 2; ++ch) {
            const int n = ch * 64 + ln;
            #pragma unroll
            for (int kb = 0; kb < 2; ++kb) {
                const int k0 = wv * 16 + kb * 8;
                float v8[8];
                #pragma unroll
                for (int j = 0; j < 8; ++j)
                    v8[j] = mfb[(size_t)(k0 + j) * HW + n];
                bf16x8 pk;
                #pragma unroll
                for (int j = 0; j < 8; ++j) pk[j] = (__bf16)v8[j];
                const int u = k0 >> 3;
                *reinterpret_cast<bf16x8*>(smem + n * 512 + ((u ^ (n & 7)) << 4)) = pk;
            }
        }
    }

    f32x4 acc[8];
    #pragma unroll
    for (int f = 0; f < 8; ++f) acc[f] = (f32x4){0.f, 0.f, 0.f, 0.f};

    // ---- persistent tile loop ----
    for (int i = 0; i < NTILE; ++i) {
        char* bcur = smem + (i & 1) * BUFB;
        char* bnxt = smem + ((i & 1) ^ 1) * BUFB;

        WAIT_LGKM0();
        hard_barrier();                    // panel[cur] staged & visible

        // issue next tile's 32 loads; they fly through K-loop + epilogue
        float v[32];
        const bool havenext = (i + 1 < NTILE);
        if (havenext) {
            const float* mfb = mfB + (size_t)(tb + i + 1) * NPB;
            #pragma unroll
            for (int ch = 0; ch < 2; ++ch) {
                const int n = ch * 64 + ln;
                #pragma unroll
                for (int kb = 0; kb < 2; ++kb) {
                    const int k0 = wv * 16 + kb * 8;
                    #pragma unroll
                    for (int j = 0; j < 8; ++j)
                        v[ch * 16 + kb * 8 + j] = mfb[(size_t)(k0 + j) * HW + n];
                }
            }
            __builtin_amdgcn_sched_barrier(0);   // pin issuance before K-loop
        }

        // K-loop: pure LDS + MFMA; wave computes its single m-tile
        if (hasmt) {
            #pragma unroll
            for (int t = 0; t < KSTEPS; ++t) {
                bf16x8 bf[8];
                #pragma unroll
                for (int f = 0; f < 8; ++f) {
                    const int off = (f * 16 + l15) * 512 + (((t * 4 + lg) ^ swz) << 4);
                    bf[f] = *reinterpret_cast<const bf16x8*>(bcur + off);
                }
                #pragma unroll
                for (int f = 0; f < 8; ++f)
                    acc[f] = __builtin_amdgcn_mfma_f32_16x16x32_bf16(
                        Af[t], bf[f], acc[f], 0, 0, 0);
            }
        }
        __builtin_amdgcn_sched_barrier(0);
        WAIT_LGKM0();
        hard_barrier();                    // all waves done reading panel[cur]

        // epilogue: 7 passes of 2 m-tiles via panel[cur] scratch [32][132] f32
        {
            const int n0 = (tb + i) * NPB;
            float* scr  = reinterpret_cast<float*>(bcur);
            float* outb = outB + n0;
            #pragma unroll
            for (int p = 0; p < 7; ++p) {
                // write pass p: waves 2p and 2p+1 (their m-tiles)
                if ((wv >> 1) == p && hasmt) {
                    const int u = wv & 1;
                    #pragma unroll
                    for (int f = 0; f < 8; ++f)
                        #pragma unroll
                        for (int r = 0; r < 4; ++r)
                            scr[(u * 16 + lg * 4 + r) * 132 + f * 16 + l15] =
                                acc[f][r];
                }
                WAIT_LGKM0();
                hard_barrier();            // scr writes visible
                // store 32 rows x 128 f32 = 1024 f32x4, one per thread
                {
                    const int row = tid >> 5, c4 = (tid & 31) << 2;
                    const int q = p * 32 + row;
                    if (q < NQ) {
                        f32x4 vv = *reinterpret_cast<const f32x4*>(&scr[row * 132 + c4]);
                        __builtin_nontemporal_store(vv,
                            reinterpret_cast<f32x4*>(outb + (size_t)q * HW + c4));
                    }
                }
                hard_barrier();            // reads of scr done before next pass
            }
        }

        // stage-write tile i+1 into panel[cur^1]; reads had ~K-loop+epilogue
        // time to land (compiler inserts the vmcnt wait on v)
        if (havenext) {
            #pragma unroll
            for (int ch = 0; ch < 2; ++ch) {
                const int n = ch * 64 + ln;
                #pragma unroll
                for (int kb = 0; kb < 2; ++kb) {
                    const int k0 = wv * 16 + kb * 8;
                    bf16x8 pk;
                    #pragma unroll
                    for (int j = 0; j < 8; ++j) pk[j] = (__bf16)v[ch * 16 + kb * 8 + j];
                    const int u = k0 >> 3;
                    *reinterpret_cast<bf16x8*>(bnxt + n * 512 + ((u ^ (n & 7)) << 4)) = pk;
                }
            }
        }

        // reset accumulators for next tile
        #pragma unroll
        for (int f = 0; f < 8; ++f) acc[f] = (f32x4){0.f, 0.f, 0.f, 0.f};
    }
}

// ---------------------------------------------------------------------------
extern "C" void kernel_launch(void* const* d_in, const int* in_sizes, int n_in,
                              void* d_out, int out_size, void* d_ws, size_t ws_size,
                              hipStream_t stream)
{
    const float* queries = (const float*)d_in[0];
    const float* mf      = (const float*)d_in[1];
    const float* w1      = (const float*)d_in[2];
    const float* b1      = (const float*)d_in[3];
    const float* w2      = (const float*)d_in[4];
    const float* b2      = (const float*)d_in[5];
    float*  out  = (float*)d_out;
    __bf16* A_ws = (__bf16*)d_ws;   // 4*13*8*512*2 = 425,984 B

    (void)hipFuncSetAttribute((const void*)mask_gemm,
                              hipFuncAttributeMaxDynamicSharedMemorySize, 2 * BUFB);

    hipLaunchKernelGGL(mlp_pack, dim3(NB * MT), dim3(1024), 0, stream,
                       queries, w1, b1, w2, b2, A_ws);
    hipLaunchKernelGGL(mask_gemm, dim3(256), dim3(GT), 2 * BUFB, stream,
                       mf, A_ws, out);
}

// Round 10
// 264.151 us; speedup vs baseline: 1.2246x; 1.0040x over previous
//
#include <hip/hip_runtime.h>
#include <hip/hip_bf16.h>

#define HIDDEN 256
#define NB 4            // batches
#define NQ 200          // queries
#define MT 13           // m-tiles of 16 (208 padded rows)
#define HW 65536        // 256*256 pixels
#define KSTEPS 8        // 256 / 32
#define NPB 128         // pixels per gemm tile
#define NTILE 8         // tiles per persistent block
#define GT 1024         // gemm threads (16 waves)
#define BUFB 65536      // bytes per LDS panel

typedef __attribute__((ext_vector_type(8))) __bf16 bf16x8;
typedef __attribute__((ext_vector_type(4))) float f32x4;

#define WAIT_LGKM0() asm volatile("s_waitcnt lgkmcnt(0)" ::: "memory")
__device__ __forceinline__ void hard_barrier() {
    __builtin_amdgcn_sched_barrier(0);
    __builtin_amdgcn_s_barrier();
    __builtin_amdgcn_sched_barrier(0);
}

// ---------------------------------------------------------------------------
// Kernel 1: mask_embed MLP -> bf16 A-fragments in d_ws (unchanged, verified).
// A_ws layout: [b][mt][ks][lane(64)][j(8)] bf16,
//   element (row = mt*16 + (lane&15), k = ks*32 + (lane>>4)*8 + j)
// ---------------------------------------------------------------------------
__global__ __launch_bounds__(1024)
void mlp_pack(const float* __restrict__ queries,
              const float* __restrict__ w1, const float* __restrict__ b1,
              const float* __restrict__ w2, const float* __restrict__ b2,
              __bf16* __restrict__ A_ws)
{
    __shared__ float qh[16][HIDDEN];
    __shared__ float wb[HIDDEN][33];
    const int blk = blockIdx.x;
    const int b = blk / MT, mt = blk % MT;
    const int tid = threadIdx.x;

    for (int idx = tid; idx < 16 * HIDDEN; idx += 1024) {
        int r = idx >> 8, c = idx & 255;
        int q = mt * 16 + r;
        qh[r][c] = (q < NQ) ? queries[((size_t)b * NQ + q) * HIDDEN + c] : 0.f;
    }
    __syncthreads();

    const int t  = tid & 255;
    const int rq = tid >> 8;
    const int sr = tid >> 2;
    const int si = tid & 3;

    float h[4];
    #pragma unroll
    for (int r = 0; r < 4; ++r) h[r] = b1[t];
    for (int cc = 0; cc < 8; ++cc) {
        const float* src = w1 + (size_t)sr * HIDDEN + cc * 32;
        float4 va = *reinterpret_cast<const float4*>(src + si * 4);
        float4 vb = *reinterpret_cast<const float4*>(src + 16 + si * 4);
        wb[sr][si*4+0] = va.x; wb[sr][si*4+1] = va.y;
        wb[sr][si*4+2] = va.z; wb[sr][si*4+3] = va.w;
        wb[sr][16+si*4+0] = vb.x; wb[sr][16+si*4+1] = vb.y;
        wb[sr][16+si*4+2] = vb.z; wb[sr][16+si*4+3] = vb.w;
        __syncthreads();
        #pragma unroll
        for (int cl = 0; cl < 32; ++cl) {
            float w = wb[t][cl];
            #pragma unroll
            for (int r = 0; r < 4; ++r)
                h[r] = fmaf(qh[rq * 4 + r][cc * 32 + cl], w, h[r]);
        }
        __syncthreads();
    }

    #pragma unroll
    for (int r = 0; r < 4; ++r) qh[rq * 4 + r][t] = fmaxf(h[r], 0.f);
    __syncthreads();

    float me[4];
    #pragma unroll
    for (int r = 0; r < 4; ++r) me[r] = b2[t];
    for (int cc = 0; cc < 8; ++cc) {
        const float* src = w2 + (size_t)sr * HIDDEN + cc * 32;
        float4 va = *reinterpret_cast<const float4*>(src + si * 4);
        float4 vb = *reinterpret_cast<const float4*>(src + 16 + si * 4);
        wb[sr][si*4+0] = va.x; wb[sr][si*4+1] = va.y;
        wb[sr][si*4+2] = va.z; wb[sr][si*4+3] = va.w;
        wb[sr][16+si*4+0] = vb.x; wb[sr][16+si*4+1] = vb.y;
        wb[sr][16+si*4+2] = vb.z; wb[sr][16+si*4+3] = vb.w;
        __syncthreads();
        #pragma unroll
        for (int cl = 0; cl < 32; ++cl) {
            float w = wb[t][cl];
            #pragma unroll
            for (int r = 0; r < 4; ++r)
                me[r] = fmaf(qh[rq * 4 + r][cc * 32 + cl], w, me[r]);
        }
        __syncthreads();
    }

    const int ks = t >> 5, g = (t >> 3) & 3, j = t & 7;
    #pragma unroll
    for (int r = 0; r < 4; ++r) {
        int row = rq * 4 + r;
        int q = mt * 16 + row;
        float v = (q < NQ) ? me[r] : 0.f;
        int lane = row + 16 * g;
        size_t addr = ((size_t)((b * MT + mt) * KSTEPS + ks)) * 512 + (size_t)lane * 8 + j;
        A_ws[addr] = (__bf16)v;
    }
}

// ---------------------------------------------------------------------------
// Kernel 2 v9: persistent pipeline, 1024 thr / 16 waves, 1 block/CU.
// amdgpu_waves_per_eu(4,4) pins the allocator's occupancy target to the
// true occupancy (16 waves/CU = 4/EU) -> 128-VGPR budget (r9 got capped
// at 64 and spilled: WRITE 271MB vs 205MB output).
// Wave wv owns m-tile wv (waves 13..15 idle in MFMA; all waves stage/store).
// Residents: Af[8]=32, acc[8]=32, v[32]=32, bf[4]=16 transient -> ~115 regs.
// Per tile i:
//   [bar: panel ready] -> issue 32 reg-loads for tile i+1 ->
//   K-loop on panel[cur] (pure LDS+MFMA) -> [bar] ->
//   epilogue on panel[cur] scratch (nontemporal 512B row stores) ->
//   cvt+ds_write tile i+1 -> panel[cur^1]  (reads got K-loop+epilogue to land)
// LDS element (n,k) at byte: n*512 + (((k>>3) ^ (n&7))<<4) + (k&7)*2.
// ---------------------------------------------------------------------------
__global__ __launch_bounds__(GT)
__attribute__((amdgpu_waves_per_eu(4, 4)))
void mask_gemm(const float* __restrict__ mf,
               const __bf16* __restrict__ A_ws,
               float* __restrict__ out)
{
    extern __shared__ char smem[];     // 2 x 64 KB panels

    const int bid = blockIdx.x;
    const int b   = bid >> 6;          // 64 blocks per batch
    const int tb  = (bid & 63) * NTILE;
    const int tid = threadIdx.x;
    const int ln  = tid & 63, wv = tid >> 6;   // wv in [0,16)
    const int l15 = ln & 15,  lg = ln >> 4;
    const bool hasmt = wv < MT;
    const int swz = l15 & 7;

    const float*  mfB  = mf  + (size_t)b * HIDDEN * HW;
    const __bf16* Ab   = A_ws + (size_t)b * (MT * KSTEPS * 512);
    float*        outB = out + (size_t)b * NQ * HW;

    // ---- A fragments: resident for the whole kernel (32 VGPR) ----
    bf16x8 Af[KSTEPS];
    if (hasmt) {
        #pragma unroll
        for (int ks = 0; ks < KSTEPS; ++ks)
            Af[ks] = *reinterpret_cast<const bf16x8*>(
                Ab + ((size_t)(wv * KSTEPS + ks)) * 512 + (size_t)ln * 8);
    }

    // ---- prologue: stage tile tb into panel 0 ----
    // wave wv stages k-rows [wv*16, wv*16+16), both 64-column halves
    {
        const float* mfb = mfB + (size_t)tb * NPB;
        #pragma unroll
        for (int ch = 0; ch < 2; ++ch) {
            const int n = ch * 64 + ln;
            #pragma unroll
            for (int kb = 0; kb < 2; ++kb) {
                const int k0 = wv * 16 + kb * 8;
                float v8[8];
                #pragma unroll
                for (int j = 0; j < 8; ++j)
                    v8[j] = mfb[(size_t)(k0 + j) * HW + n];
                bf16x8 pk;
                #pragma unroll
                for (int j = 0; j < 8; ++j) pk[j] = (__bf16)v8[j];
                const int u = k0 >> 3;
                *reinterpret_cast<bf16x8*>(smem + n * 512 + ((u ^ (n & 7)) << 4)) = pk;
            }
        }
    }

    f32x4 acc[8];
    #pragma unroll
    for (int f = 0; f < 8; ++f) acc[f] = (f32x4){0.f, 0.f, 0.f, 0.f};

    // ---- persistent tile loop ----
    for (int i = 0; i < NTILE; ++i) {
        char* bcur = smem + (i & 1) * BUFB;
        char* bnxt = smem + ((i & 1) ^ 1) * BUFB;

        WAIT_LGKM0();
        hard_barrier();                    // panel[cur] staged & visible

        // issue next tile's 32 loads; they fly through K-loop + epilogue
        float v[32];
        const bool havenext = (i + 1 < NTILE);
        if (havenext) {
            const float* mfb = mfB + (size_t)(tb + i + 1) * NPB;
            #pragma unroll
            for (int ch = 0; ch < 2; ++ch) {
                const int n = ch * 64 + ln;
                #pragma unroll
                for (int kb = 0; kb < 2; ++kb) {
                    const int k0 = wv * 16 + kb * 8;
                    #pragma unroll
                    for (int j = 0; j < 8; ++j)
                        v[ch * 16 + kb * 8 + j] = mfb[(size_t)(k0 + j) * HW + n];
                }
            }
            __builtin_amdgcn_sched_barrier(0);   // pin issuance before K-loop
        }

        // K-loop: pure LDS + MFMA; wave computes its single m-tile.
        // B-frags read in groups of 4 (16 transient VGPRs, not 32).
        if (hasmt) {
            #pragma unroll
            for (int t = 0; t < KSTEPS; ++t) {
                #pragma unroll
                for (int fg = 0; fg < 2; ++fg) {
                    bf16x8 bf[4];
                    #pragma unroll
                    for (int f2 = 0; f2 < 4; ++f2) {
                        const int f = fg * 4 + f2;
                        const int off = (f * 16 + l15) * 512 + (((t * 4 + lg) ^ swz) << 4);
                        bf[f2] = *reinterpret_cast<const bf16x8*>(bcur + off);
                    }
                    #pragma unroll
                    for (int f2 = 0; f2 < 4; ++f2)
                        acc[fg * 4 + f2] = __builtin_amdgcn_mfma_f32_16x16x32_bf16(
                            Af[t], bf[f2], acc[fg * 4 + f2], 0, 0, 0);
                }
            }
        }
        __builtin_amdgcn_sched_barrier(0);
        WAIT_LGKM0();
        hard_barrier();                    // all waves done reading panel[cur]

        // epilogue: 7 passes of 2 m-tiles via panel[cur] scratch [32][132] f32
        {
            const int n0 = (tb + i) * NPB;
            float* scr  = reinterpret_cast<float*>(bcur);
            float* outb = outB + n0;
            #pragma unroll
            for (int p = 0; p < 7; ++p) {
                // write pass p: waves 2p and 2p+1 (their m-tiles)
                if ((wv >> 1) == p && hasmt) {
                    const int u = wv & 1;
                    #pragma unroll
                    for (int f = 0; f < 8; ++f)
                        #pragma unroll
                        for (int r = 0; r < 4; ++r)
                            scr[(u * 16 + lg * 4 + r) * 132 + f * 16 + l15] =
                                acc[f][r];
                }
                WAIT_LGKM0();
                hard_barrier();            // scr writes visible
                // store 32 rows x 128 f32 = 1024 f32x4, one per thread
                {
                    const int row = tid >> 5, c4 = (tid & 31) << 2;
                    const int q = p * 32 + row;
                    if (q < NQ) {
                        f32x4 vv = *reinterpret_cast<const f32x4*>(&scr[row * 132 + c4]);
                        __builtin_nontemporal_store(vv,
                            reinterpret_cast<f32x4*>(outb + (size_t)q * HW + c4));
                    }
                }
                hard_barrier();            // reads of scr done before next pass
            }
        }

        // stage-write tile i+1 into panel[cur^1]; reads had ~K-loop+epilogue
        // time to land (compiler inserts the vmcnt wait on v)
        if (havenext) {
            #pragma unroll
            for (int ch = 0; ch < 2; ++ch) {
                const int n = ch * 64 + ln;
                #pragma unroll
                for (int kb = 0; kb < 2; ++kb) {
                    const int k0 = wv * 16 + kb * 8;
                    bf16x8 pk;
                    #pragma unroll
                    for (int j = 0; j < 8; ++j) pk[j] = (__bf16)v[ch * 16 + kb * 8 + j];
                    const int u = k0 >> 3;
                    *reinterpret_cast<bf16x8*>(bnxt + n * 512 + ((u ^ (n & 7)) << 4)) = pk;
                }
            }
        }

        // reset accumulators for next tile
        #pragma unroll
        for (int f = 0; f < 8; ++f) acc[f] = (f32x4){0.f, 0.f, 0.f, 0.f};
    }
}

// ---------------------------------------------------------------------------
extern "C" void kernel_launch(void* const* d_in, const int* in_sizes, int n_in,
                              void* d_out, int out_size, void* d_ws, size_t ws_size,
                              hipStream_t stream)
{
    const float* queries = (const float*)d_in[0];
    const float* mf      = (const float*)d_in[1];
    const float* w1      = (const float*)d_in[2];
    const float* b1      = (const float*)d_in[3];
    const float* w2      = (const float*)d_in[4];
    const float* b2      = (const float*)d_in[5];
    float*  out  = (float*)d_out;
    __bf16* A_ws = (__bf16*)d_ws;   // 4*13*8*512*2 = 425,984 B

    (void)hipFuncSetAttribute((const void*)mask_gemm,
                              hipFuncAttributeMaxDynamicSharedMemorySize, 2 * BUFB);

    hipLaunchKernelGGL(mlp_pack, dim3(NB * MT), dim3(1024), 0, stream,
                       queries, w1, b1, w2, b2, A_ws);
    hipLaunchKernelGGL(mask_gemm, dim3(256), dim3(GT), 2 * BUFB, stream,
                       mf, A_ws, out);
}

// Round 11
// 127.414 us; speedup vs baseline: 2.5388x; 2.0732x over previous
//
#include <hip/hip_runtime.h>
#include <hip/hip_bf16.h>

#define HIDDEN 256
#define NB 4            // batches
#define NQ 200          // queries
#define MT 13           // m-tiles of 16 (208 padded rows)
#define HW 65536        // 256*256 pixels
#define KSTEPS 8        // 256 / 32
#define NPB 64          // pixels per gemm tile
#define NTILE 16        // tiles per persistent block
#define GT 512          // gemm threads (8 waves)
#define HBB 16384       // half-panel bytes: 64 n x 128 k bf16
#define ABYTES (MT * KSTEPS * 1024)          // 106496: A frags in LDS
#define SMEM_TOTAL (ABYTES + 3 * HBB)        // 155648 <= 160 KB

typedef __attribute__((ext_vector_type(8))) __bf16 bf16x8;
typedef __attribute__((ext_vector_type(4))) float f32x4;

#define WAITVM0()    asm volatile("s_waitcnt vmcnt(0)" ::: "memory")
#define WAIT_LGKM0() asm volatile("s_waitcnt lgkmcnt(0)" ::: "memory")
__device__ __forceinline__ void hard_barrier() {
    __builtin_amdgcn_sched_barrier(0);
    __builtin_amdgcn_s_barrier();
    __builtin_amdgcn_sched_barrier(0);
}

// async global->LDS, 16 B per lane; LDS dest = wave-uniform base + lane*16
__device__ __forceinline__ void gload_lds16(const void* g, void* l) {
    __builtin_amdgcn_global_load_lds(
        (const __attribute__((address_space(1))) void*)g,
        (__attribute__((address_space(3))) void*)l, 16, 0, 0);
}

// ---------------------------------------------------------------------------
// Kernel 1: mask_embed MLP -> bf16 A-fragments in d_ws (unchanged, verified).
// A_ws layout: [b][mt][ks][lane(64)][j(8)] bf16,
//   element (row = mt*16 + (lane&15), k = ks*32 + (lane>>4)*8 + j)
// ---------------------------------------------------------------------------
__global__ __launch_bounds__(1024)
void mlp_pack(const float* __restrict__ queries,
              const float* __restrict__ w1, const float* __restrict__ b1,
              const float* __restrict__ w2, const float* __restrict__ b2,
              __bf16* __restrict__ A_ws)
{
    __shared__ float qh[16][HIDDEN];
    __shared__ float wb[HIDDEN][33];
    const int blk = blockIdx.x;
    const int b = blk / MT, mt = blk % MT;
    const int tid = threadIdx.x;

    for (int idx = tid; idx < 16 * HIDDEN; idx += 1024) {
        int r = idx >> 8, c = idx & 255;
        int q = mt * 16 + r;
        qh[r][c] = (q < NQ) ? queries[((size_t)b * NQ + q) * HIDDEN + c] : 0.f;
    }
    __syncthreads();

    const int t  = tid & 255;
    const int rq = tid >> 8;
    const int sr = tid >> 2;
    const int si = tid & 3;

    float h[4];
    #pragma unroll
    for (int r = 0; r < 4; ++r) h[r] = b1[t];
    for (int cc = 0; cc < 8; ++cc) {
        const float* src = w1 + (size_t)sr * HIDDEN + cc * 32;
        float4 va = *reinterpret_cast<const float4*>(src + si * 4);
        float4 vb = *reinterpret_cast<const float4*>(src + 16 + si * 4);
        wb[sr][si*4+0] = va.x; wb[sr][si*4+1] = va.y;
        wb[sr][si*4+2] = va.z; wb[sr][si*4+3] = va.w;
        wb[sr][16+si*4+0] = vb.x; wb[sr][16+si*4+1] = vb.y;
        wb[sr][16+si*4+2] = vb.z; wb[sr][16+si*4+3] = vb.w;
        __syncthreads();
        #pragma unroll
        for (int cl = 0; cl < 32; ++cl) {
            float w = wb[t][cl];
            #pragma unroll
            for (int r = 0; r < 4; ++r)
                h[r] = fmaf(qh[rq * 4 + r][cc * 32 + cl], w, h[r]);
        }
        __syncthreads();
    }

    #pragma unroll
    for (int r = 0; r < 4; ++r) qh[rq * 4 + r][t] = fmaxf(h[r], 0.f);
    __syncthreads();

    float me[4];
    #pragma unroll
    for (int r = 0; r < 4; ++r) me[r] = b2[t];
    for (int cc = 0; cc < 8; ++cc) {
        const float* src = w2 + (size_t)sr * HIDDEN + cc * 32;
        float4 va = *reinterpret_cast<const float4*>(src + si * 4);
        float4 vb = *reinterpret_cast<const float4*>(src + 16 + si * 4);
        wb[sr][si*4+0] = va.x; wb[sr][si*4+1] = va.y;
        wb[sr][si*4+2] = va.z; wb[sr][si*4+3] = va.w;
        wb[sr][16+si*4+0] = vb.x; wb[sr][16+si*4+1] = vb.y;
        wb[sr][16+si*4+2] = vb.z; wb[sr][16+si*4+3] = vb.w;
        __syncthreads();
        #pragma unroll
        for (int cl = 0; cl < 32; ++cl) {
            float w = wb[t][cl];
            #pragma unroll
            for (int r = 0; r < 4; ++r)
                me[r] = fmaf(qh[rq * 4 + r][cc * 32 + cl], w, me[r]);
        }
        __syncthreads();
    }

    const int ks = t >> 5, g = (t >> 3) & 3, j = t & 7;
    #pragma unroll
    for (int r = 0; r < 4; ++r) {
        int row = rq * 4 + r;
        int q = mt * 16 + row;
        float v = (q < NQ) ? me[r] : 0.f;
        int lane = row + 16 * g;
        size_t addr = ((size_t)((b * MT + mt) * KSTEPS + ks)) * 512 + (size_t)lane * 8 + j;
        A_ws[addr] = (__bf16)v;
    }
}

// ---------------------------------------------------------------------------
// Kernel 2 v10: persistent half-panel ring pipeline, ~90-VGPR working set.
// 256 blocks (1/CU), 512 thr / 8 waves, 152 KB LDS:
//   [A frags 104 KB (staged once via gload_lds)] [3 x 16 KB B half-panels]
// Wave wv owns m-tiles {wv, wv+8}; acc[2][4] = 32 regs; staging v[16].
// Slot s (= tile s>>1, k-half s&1), buffers rotate s%3:
//   issue 16 reads for slot s+1 -> compute 4 ksteps (pure LDS+MFMA) ->
//   [odd slot: epilogue, exactly 7 nt-stores/thread, scr = freed h0 buffer]
//   -> ds_write slot s+1 (compiler inserts counted vmcnt for v) -> barrier.
// B half-panel layout: elem (n,k): byte n*256 + (((k>>3) ^ (n&7))<<4) + (k&7)*2
// ---------------------------------------------------------------------------
__global__ __launch_bounds__(GT)
void mask_gemm(const float* __restrict__ mf,
               const __bf16* __restrict__ A_ws,
               float* __restrict__ out)
{
    extern __shared__ char smem[];
    char* Ar = smem;                   // A fragment region
    char* HB = smem + ABYTES;          // 3 half-panel buffers

    const int bid = blockIdx.x;
    const int b   = bid >> 6;                      // 64 blocks per batch
    const int px0 = (bid & 63) * (NTILE * NPB);    // 1024-px contiguous span
    const int tid = threadIdx.x;
    const int ln  = tid & 63, wv = tid >> 6;
    const int l15 = ln & 15,  lg = ln >> 4;
    const bool has2 = (wv + 8) < MT;
    const int sn = ln;                 // staging: n within tile
    const int su = wv;                 // staging: unit pair index

    const float*  mfB  = mf  + (size_t)b * HIDDEN * HW;
    const __bf16* Ab   = A_ws + (size_t)b * (MT * KSTEPS * 512);
    float*        outB = out + (size_t)b * NQ * HW;

    // ---- stage A panel into LDS (once): 13 frags per wave, lane-linear ----
    for (int fi = wv; fi < MT * KSTEPS; fi += 8)
        gload_lds16(Ab + (size_t)fi * 512 + (size_t)ln * 8,
                    Ar + fi * 1024 + ln * 16);

    // ---- slot 0 reads ----
    float v[16];
    {
        const float* src = mfB + px0 + sn;          // tile 0, half 0
        #pragma unroll
        for (int c = 0; c < 2; ++c)
            #pragma unroll
            for (int j = 0; j < 8; ++j)
                v[c * 8 + j] = src[(size_t)((su * 2 + c) * 8 + j) * HW];
    }
    WAITVM0();                          // A gloads + slot-0 reads complete
    #pragma unroll
    for (int c = 0; c < 2; ++c) {
        bf16x8 pk;
        #pragma unroll
        for (int j = 0; j < 8; ++j) pk[j] = (__bf16)v[c * 8 + j];
        const int u = su * 2 + c;
        *reinterpret_cast<bf16x8*>(HB + sn * 256 + ((u ^ (sn & 7)) << 4)) = pk;
    }
    WAIT_LGKM0();
    hard_barrier();

    f32x4 acc[2][4];
    #pragma unroll
    for (int ii = 0; ii < 2; ++ii)
        #pragma unroll
        for (int f = 0; f < 4; ++f) acc[ii][f] = (f32x4){0.f, 0.f, 0.f, 0.f};

    // ---- slot loop: 32 slots = 16 tiles x 2 k-halves ----
    for (int s = 0; s < 2 * NTILE; ++s) {
        const int i = s >> 1, h = s & 1;
        char* bcur = HB + (s % 3) * HBB;
        const bool hn = (s + 1) < 2 * NTILE;

        // issue reads for slot s+1 (fly through compute + epilogue)
        if (hn) {
            const int i2 = (s + 1) >> 1, h2 = (s + 1) & 1;
            const float* src = mfB + (size_t)h2 * 128 * HW + px0 + i2 * NPB + sn;
            #pragma unroll
            for (int c = 0; c < 2; ++c)
                #pragma unroll
                for (int j = 0; j < 8; ++j)
                    v[c * 8 + j] = src[(size_t)((su * 2 + c) * 8 + j) * HW];
            __builtin_amdgcn_sched_barrier(0);   // pin issuance before K-loop
        }

        // compute 4 ksteps from bcur (pure LDS + MFMA, zero vmem)
        #pragma unroll
        for (int kk = 0; kk < 4; ++kk) {
            const int t = h * 4 + kk;
            bf16x8 a0 = *reinterpret_cast<const bf16x8*>(
                Ar + (wv * KSTEPS + t) * 1024 + ln * 16);
            bf16x8 a1;
            if (has2)
                a1 = *reinterpret_cast<const bf16x8*>(
                    Ar + ((wv + 8) * KSTEPS + t) * 1024 + ln * 16);
            #pragma unroll
            for (int f = 0; f < 4; ++f) {
                bf16x8 bf = *reinterpret_cast<const bf16x8*>(
                    bcur + (f * 16 + l15) * 256 + (((kk * 4 + lg) ^ (l15 & 7)) << 4));
                acc[0][f] = __builtin_amdgcn_mfma_f32_16x16x32_bf16(
                    a0, bf, acc[0][f], 0, 0, 0);
                if (has2)
                    acc[1][f] = __builtin_amdgcn_mfma_f32_16x16x32_bf16(
                        a1, bf, acc[1][f], 0, 0, 0);
            }
        }

        // epilogue at odd slots: tile i done; scr = this tile's freed h0 buffer
        if (h == 1) {
            float* scr = reinterpret_cast<float*>(HB + ((s + 2) % 3) * HBB);
            const int n0 = px0 + i * NPB;
            float* outb = outB + n0;
            #pragma unroll
            for (int p = 0; p < 7; ++p) {
                WAIT_LGKM0();
                hard_barrier();              // prior pass reads / K-loop done
                #pragma unroll
                for (int u = 0; u < 2; ++u) {
                    const int mt = 2 * p + u;
                    if (mt < MT && (mt & 7) == wv) {
                        const int ii = mt >> 3;
                        #pragma unroll
                        for (int f = 0; f < 4; ++f)
                            #pragma unroll
                            for (int r = 0; r < 4; ++r)
                                scr[(u * 16 + lg * 4 + r) * 68 + f * 16 + l15] =
                                    acc[ii][f][r];
                    }
                }
                WAIT_LGKM0();
                hard_barrier();              // scr writes visible
                // exactly one 16B nt-store per thread per pass (clamped rows
                // duplicate row 199's store -> same addr, same value, benign)
                {
                    int row = tid >> 4;
                    const int c = (tid & 15) << 2;
                    int q = p * 32 + row;
                    if (q >= NQ) { row -= (q - (NQ - 1)); q = NQ - 1; }
                    f32x4 vv = *reinterpret_cast<const f32x4*>(scr + row * 68 + c);
                    __builtin_nontemporal_store(vv,
                        reinterpret_cast<f32x4*>(outb + (size_t)q * HW + c));
                }
            }
            #pragma unroll
            for (int ii = 0; ii < 2; ++ii)
                #pragma unroll
                for (int f = 0; f < 4; ++f)
                    acc[ii][f] = (f32x4){0.f, 0.f, 0.f, 0.f};
        }

        // boundary: write slot s+1 into its ring buffer (untouched this slot);
        // compiler inserts the counted vmcnt wait for v's loads.
        if (hn) {
            char* bnxt = HB + ((s + 1) % 3) * HBB;
            #pragma unroll
            for (int c = 0; c < 2; ++c) {
                bf16x8 pk;
                #pragma unroll
                for (int j = 0; j < 8; ++j) pk[j] = (__bf16)v[c * 8 + j];
                const int u = su * 2 + c;
                *reinterpret_cast<bf16x8*>(bnxt + sn * 256 + ((u ^ (sn & 7)) << 4)) = pk;
            }
        }
        WAIT_LGKM0();
        hard_barrier();
    }
}

// ---------------------------------------------------------------------------
extern "C" void kernel_launch(void* const* d_in, const int* in_sizes, int n_in,
                              void* d_out, int out_size, void* d_ws, size_t ws_size,
                              hipStream_t stream)
{
    const float* queries = (const float*)d_in[0];
    const float* mf      = (const float*)d_in[1];
    const float* w1      = (const float*)d_in[2];
    const float* b1      = (const float*)d_in[3];
    const float* w2      = (const float*)d_in[4];
    const float* b2      = (const float*)d_in[5];
    float*  out  = (float*)d_out;
    __bf16* A_ws = (__bf16*)d_ws;   // 4*13*8*512*2 = 425,984 B

    (void)hipFuncSetAttribute((const void*)mask_gemm,
                              hipFuncAttributeMaxDynamicSharedMemorySize,
                              SMEM_TOTAL);

    hipLaunchKernelGGL(mlp_pack, dim3(NB * MT), dim3(1024), 0, stream,
                       queries, w1, b1, w2, b2, A_ws);
    hipLaunchKernelGGL(mask_gemm, dim3(256), dim3(GT), SMEM_TOTAL, stream,
                       mf, A_ws, out);
}